// Round 9
// baseline (735.085 us; speedup 1.0000x reference)
//
#include <hip/hip_runtime.h>
#include <hip/hip_cooperative_groups.h>

// FFF tree-routing MLP, MI355X — fp32 I/O. Round 14: cooperative mega-kernel.
//
// R13 post-mortem: compaction WON (240.9->224.9, new best). phaseA stable at
// 68.3us = LLC-BW floor (786MB @ ~11.6TB/s) — model holds. Remaining 156us =
// transpose(~30) + scatter(~12) + phaseB(~55) + 3 gaps. Transpose is
// INDEPENDENT of phaseA and stresses HBM (67MB) while phaseA stresses LLC
// (2.6 of 6.3 TB/s HBM used) -> full overlap possible. R14: one cooperative
// kernel, 1024 blocks x 256 thr, 32KB dyn LDS (5 blocks/CU max -> 1024
// co-resident guaranteed). Stages: (0) zero hist/cnt; (1) interleaved
// 2 transpose tiles + 2 phaseA quads per block, even/odd blocks in opposite
// order so ~half the device does HBM tiles while half does LLC quads;
// (2) blocks 0-31 scatter_scan; (3) phaseB_cols units x2. grid.sync()
// between stages + __threadfence for cross-XCD visibility. All stage bodies
// are VERBATIM R13 code (bit-identical FP). Host falls back to the R13
// 4-launch path if the cooperative launch errors.

namespace cg = cooperative_groups;

#define D_IN    2048
#define D_OUT   2048
#define DEPTHP1 12
#define N_NODES 4095
#define N_TOK   8192
#define N_LEAF  2048
#define MEGA_G  1024

typedef float f4 __attribute__((ext_vector_type(4)));

// ===================== cooperative mega-kernel =============================
__global__ __launch_bounds__(256) void fff_mega(
    const float* __restrict__ x,        // [N_TOK, D_IN]
    const float* __restrict__ w_in,     // [N_NODES, D_IN]
    const float* __restrict__ w_out,    // [D_OUT, N_NODES]
    float* __restrict__ w_out_t,        // [N_NODES, D_OUT]
    float* __restrict__ g_all,          // [N_TOK, 12]
    int* __restrict__ leaf,             // [N_TOK]
    int* __restrict__ hc,               // hist[2048] cnt[2048]
    int* __restrict__ order,            // [N_TOK]
    float* __restrict__ g_sorted,       // [N_TOK, 12]
    int* __restrict__ lf_sorted,        // [N_TOK]
    float* __restrict__ out) {          // [N_TOK, D_OUT]
    extern __shared__ char smem[];      // 32 KB, reused per stage
    cg::grid_group grid = cg::this_grid();
    const int bid = blockIdx.x;         // 0..1023
    const int tid = threadIdx.x;        // 0..255

    // ---- stage 0: zero hist+cnt (4096 ints, 4 per block) ----
    if (tid < 4) hc[bid * 4 + tid] = 0;
    __threadfence();
    grid.sync();

    // ---- stage 1: interleaved transpose tiles + phaseA quads ----
    // Block owns tiles {bid, bid+1024} and quads {bid, bid+1024}; even blocks
    // run quad,tile,quad,tile; odd run tile,quad,tile,quad (resource mix).
    int seq[4];
    if ((bid & 1) == 0) {
        seq[0] = 2048 + bid; seq[1] = bid;
        seq[2] = 3072 + bid; seq[3] = 1024 + bid;
    } else {
        seq[0] = bid;        seq[1] = 2048 + bid;
        seq[2] = 1024 + bid; seq[3] = 3072 + bid;
    }
#pragma unroll
    for (int s = 0; s < 4; s++) {
        __syncthreads();                // LDS reuse fence between units
        const int u = seq[s];
        if (u < 2048) {
            // -- transpose tile u (verbatim R13 body) --
            float (*tile)[65] = (float(*)[65])smem;   // 16.64 KB
            const int tx = tid & 63;
            const int ty = tid >> 6;
            const int n0 = (u & 63) * 64;
            const int j0 = (u >> 6) * 64;
            const int n = n0 + tx;
#pragma unroll
            for (int k = 0; k < 16; k++) {
                const int r = ty * 16 + k;
                if (n < N_NODES)
                    tile[r][tx] = w_out[(size_t)(j0 + r) * N_NODES + n];
            }
            __syncthreads();
#pragma unroll
            for (int k = 0; k < 16; k++) {
                const int r = ty * 16 + k;
                const int nn = n0 + r;
                if (nn < N_NODES)
                    w_out_t[(size_t)nn * D_OUT + (j0 + tx)] = tile[tx][r];
            }
        } else {
            // -- phaseA quad u-2048 (verbatim R13 body) --
            const int q     = u - 2048;
            const int wave  = tid >> 6;
            const int lane  = tid & 63;
            const int token = q * 4 + wave;
            float4* xw = (float4*)smem + wave * (D_IN / 4);
            const float4* xrow = (const float4*)(x + (size_t)token * D_IN);
#pragma unroll
            for (int c = 0; c < 8; c++) xw[lane + 64 * c] = xrow[lane + 64 * c];
            // Same-wave produce->consume; compiler inserts lgkmcnt wait.
            int cur = 0;
#pragma unroll
            for (int l = 0; l < DEPTHP1; l++) {
                const float4* wrow = (const float4*)(w_in + (size_t)cur * D_IN);
                float p0 = 0.f, p1 = 0.f, p2 = 0.f, p3 = 0.f;
#pragma unroll
                for (int c = 0; c < 8; c++) {
                    const float4 wc = wrow[lane + 64 * c];
                    const float4 xc = xw[lane + 64 * c];
                    float* p = (c < 2) ? &p0 : (c < 4) ? &p1 : (c < 6) ? &p2 : &p3;
                    *p += wc.x * xc.x + wc.y * xc.y + wc.z * xc.z + wc.w * xc.w;
                }
                float part = (p0 + p1) + (p2 + p3);
#pragma unroll
                for (int off = 32; off >= 1; off >>= 1)
                    part += __shfl_xor(part, off, 64);
                const float score = part;
                cur = 2 * cur + 1 + (score >= 0.f ? 1 : 0);
                const float g =
                    0.5f * score * (1.0f + erff(score * 0.70710678118654752f));
                if (lane == 0) g_all[token * DEPTHP1 + l] = g;
            }
            if (lane == 0) {
                const int leafid = ((cur - 1) >> 1) - (N_LEAF - 1);
                leaf[token] = leafid;
                atomicAdd(&hc[leafid], 1);          // hist, 2048 bins
            }
        }
    }
    __threadfence();
    grid.sync();

    // ---- stage 2: scatter with fused in-block scan (blocks 0..31) ----
    if (bid < 32) {
        int* voff    = (int*)smem;          // 8 KB exclusive offsets
        int* partial = (int*)smem + N_LEAF; // 1 KB
        const int* hist = hc;
        int* cnt = hc + N_LEAF;
        int v[8];
        int sum = 0;
#pragma unroll
        for (int k = 0; k < 8; k++) {
            v[k] = hist[tid * 8 + k];
            sum += v[k];
        }
        partial[tid] = sum;
        __syncthreads();
        for (int off = 1; off < 256; off <<= 1) {
            const int pv = partial[tid];
            const int po = (tid >= off) ? partial[tid - off] : 0;
            __syncthreads();
            partial[tid] = pv + po;
            __syncthreads();
        }
        int base = (tid > 0) ? partial[tid - 1] : 0;
#pragma unroll
        for (int k = 0; k < 8; k++) {
            voff[tid * 8 + k] = base;
            base += v[k];
        }
        __syncthreads();

        const int tok = bid * 256 + tid;    // N_TOK == 32*256 exactly
        const int lf  = leaf[tok];
        const int pos = voff[lf] + atomicAdd(&cnt[lf], 1);
        order[pos] = tok;
        lf_sorted[pos] = lf;
#pragma unroll
        for (int l = 0; l < DEPTHP1; l++)
            g_sorted[(size_t)pos * DEPTHP1 + l] =
                g_all[(size_t)tok * DEPTHP1 + l];
    }
    __threadfence();
    grid.sync();

    // ---- stage 3: phaseB_cols units (2 per block, verbatim R13 body) ----
    for (int u = bid; u < 2048; u += MEGA_G) {
        const int xcd = u & 7;
        const int j   = u >> 3;               // 0..255
        const int tr  = xcd * 128 + (j >> 1); // 0..1023 token-range (8 tokens)
        const int ct  = j & 1;                // column half
        const size_t coff = (size_t)ct * 1024 + (size_t)tid * 4;

        const int start = tr * 8;
        const int end   = start + 8;
        int pos = start;
        while (pos < end) {
            const int lf = lf_sorted[pos];    // block-uniform (scalar)
            const int L  = lf + N_LEAF;
            f4 w[DEPTHP1];
#pragma unroll
            for (int l = 0; l < DEPTHP1; l++) {
                const int node = (L >> (DEPTHP1 - 1 - l)) - 1;
                w[l] = *(const f4*)(w_out_t + (size_t)node * D_OUT + coff);
            }
            do {
                const int tok = order[pos];
                const float* gp = g_sorted + (size_t)pos * DEPTHP1;
                f4 acc = {0.f, 0.f, 0.f, 0.f};
#pragma unroll
                for (int l = 0; l < DEPTHP1; l++)
                    acc += gp[l] * w[l];      // ascending l: R13 FP order
                __builtin_nontemporal_store(
                    acc, (f4*)(out + (size_t)tok * D_OUT + coff));
                pos++;
            } while (pos < end && lf_sorted[pos] == lf);
        }
    }
}

// ===================== R13 kernels (fallback path) =========================
__global__ __launch_bounds__(256) void transpose_wout64z(
    const float* __restrict__ in, float* __restrict__ out,
    int* __restrict__ hc) {
    __shared__ float tile[64][65];
    const int fb = blockIdx.y * 64 + blockIdx.x;
    const int tx = threadIdx.x;
    const int ty = threadIdx.y;
    if (fb < 16) {
        const int i = fb * 256 + ty * 64 + tx;
        hc[i] = 0;
    }
    const int n0 = blockIdx.x * 64;
    const int j0 = blockIdx.y * 64;
    const int n = n0 + tx;
#pragma unroll
    for (int k = 0; k < 16; k++) {
        const int r = ty * 16 + k;
        if (n < N_NODES) tile[r][tx] = in[(size_t)(j0 + r) * N_NODES + n];
    }
    __syncthreads();
#pragma unroll
    for (int k = 0; k < 16; k++) {
        const int r = ty * 16 + k;
        const int nn = n0 + r;
        if (nn < N_NODES) out[(size_t)nn * D_OUT + (j0 + tx)] = tile[tx][r];
    }
}

__global__ __launch_bounds__(256) void phaseA(
    const float* __restrict__ x, const float* __restrict__ w_in,
    float* __restrict__ g_all, int* __restrict__ leaf,
    int* __restrict__ hist) {
    extern __shared__ float xs[];
    const int wave  = threadIdx.x >> 6;
    const int lane  = threadIdx.x & 63;
    const int token = blockIdx.x * 4 + wave;
    float4* xw = (float4*)(xs) + wave * (D_IN / 4);
    const float4* xrow = (const float4*)(x + (size_t)token * D_IN);
#pragma unroll
    for (int c = 0; c < 8; c++) xw[lane + 64 * c] = xrow[lane + 64 * c];
    int cur = 0;
#pragma unroll
    for (int l = 0; l < DEPTHP1; l++) {
        const float4* wrow = (const float4*)(w_in + (size_t)cur * D_IN);
        float p0 = 0.f, p1 = 0.f, p2 = 0.f, p3 = 0.f;
#pragma unroll
        for (int c = 0; c < 8; c++) {
            const float4 wc = wrow[lane + 64 * c];
            const float4 xc = xw[lane + 64 * c];
            float* p = (c < 2) ? &p0 : (c < 4) ? &p1 : (c < 6) ? &p2 : &p3;
            *p += wc.x * xc.x + wc.y * xc.y + wc.z * xc.z + wc.w * xc.w;
        }
        float part = (p0 + p1) + (p2 + p3);
#pragma unroll
        for (int off = 32; off >= 1; off >>= 1)
            part += __shfl_xor(part, off, 64);
        const float score = part;
        cur = 2 * cur + 1 + (score >= 0.f ? 1 : 0);
        const float g = 0.5f * score * (1.0f + erff(score * 0.70710678118654752f));
        if (lane == 0) g_all[token * DEPTHP1 + l] = g;
    }
    if (lane == 0) {
        const int leafid = ((cur - 1) >> 1) - (N_LEAF - 1);
        leaf[token] = leafid;
        atomicAdd(&hist[leafid], 1);
    }
}

__global__ __launch_bounds__(256) void scatter_scan(
    const int* __restrict__ leaf, const int* __restrict__ hist,
    int* __restrict__ cnt, const float* __restrict__ g_all,
    int* __restrict__ order, float* __restrict__ g_sorted,
    int* __restrict__ lf_sorted) {
    __shared__ int voff[N_LEAF];
    __shared__ int partial[256];
    const int t = threadIdx.x;
    int v[8];
    int sum = 0;
#pragma unroll
    for (int k = 0; k < 8; k++) {
        v[k] = hist[t * 8 + k];
        sum += v[k];
    }
    partial[t] = sum;
    __syncthreads();
    for (int off = 1; off < 256; off <<= 1) {
        const int pv = partial[t];
        const int po = (t >= off) ? partial[t - off] : 0;
        __syncthreads();
        partial[t] = pv + po;
        __syncthreads();
    }
    int base = (t > 0) ? partial[t - 1] : 0;
#pragma unroll
    for (int k = 0; k < 8; k++) {
        voff[t * 8 + k] = base;
        base += v[k];
    }
    __syncthreads();
    const int tok = blockIdx.x * 256 + t;
    const int lf  = leaf[tok];
    const int pos = voff[lf] + atomicAdd(&cnt[lf], 1);
    order[pos] = tok;
    lf_sorted[pos] = lf;
#pragma unroll
    for (int l = 0; l < DEPTHP1; l++)
        g_sorted[(size_t)pos * DEPTHP1 + l] = g_all[(size_t)tok * DEPTHP1 + l];
}

__global__ __launch_bounds__(256) void phaseB_cols(
    const float* __restrict__ w_out_t, const float* __restrict__ g_sorted,
    const int* __restrict__ order, const int* __restrict__ lf_sorted,
    float* __restrict__ out) {
    const int b   = blockIdx.x;
    const int xcd = b & 7;
    const int j   = b >> 3;
    const int tr  = xcd * 128 + (j >> 1);
    const int ct  = j & 1;
    const int t   = threadIdx.x;
    const size_t coff = (size_t)ct * 1024 + (size_t)t * 4;
    const int start = tr * 8;
    const int end   = start + 8;
    int pos = start;
    while (pos < end) {
        const int lf = lf_sorted[pos];
        const int L  = lf + N_LEAF;
        f4 w[DEPTHP1];
#pragma unroll
        for (int l = 0; l < DEPTHP1; l++) {
            const int node = (L >> (DEPTHP1 - 1 - l)) - 1;
            w[l] = *(const f4*)(w_out_t + (size_t)node * D_OUT + coff);
        }
        do {
            const int tok = order[pos];
            const float* gp = g_sorted + (size_t)pos * DEPTHP1;
            f4 acc = {0.f, 0.f, 0.f, 0.f};
#pragma unroll
            for (int l = 0; l < DEPTHP1; l++)
                acc += gp[l] * w[l];
            __builtin_nontemporal_store(
                acc, (f4*)(out + (size_t)tok * D_OUT + coff));
            pos++;
        } while (pos < end && lf_sorted[pos] == lf);
    }
}

// ===================== small-workspace fallbacks ===========================
__global__ __launch_bounds__(256) void transpose_wout64(
    const float* __restrict__ in, float* __restrict__ out) {
    __shared__ float tile[64][65];
    const int n0 = blockIdx.x * 64;
    const int j0 = blockIdx.y * 64;
    const int tx = threadIdx.x;
    const int ty = threadIdx.y;
    const int n = n0 + tx;
#pragma unroll
    for (int k = 0; k < 16; k++) {
        const int r = ty * 16 + k;
        if (n < N_NODES) tile[r][tx] = in[(size_t)(j0 + r) * N_NODES + n];
    }
    __syncthreads();
#pragma unroll
    for (int k = 0; k < 16; k++) {
        const int r = ty * 16 + k;
        const int nn = n0 + r;
        if (nn < N_NODES) out[(size_t)nn * D_OUT + (j0 + tx)] = tile[tx][r];
    }
}

template <bool TRANSPOSED>
__global__ __launch_bounds__(256) void fff_fused(
    const float* __restrict__ x, const float* __restrict__ w_in,
    const float* __restrict__ w_out, float* __restrict__ out) {
    const int wave  = threadIdx.x >> 6;
    const int lane  = threadIdx.x & 63;
    const int token = blockIdx.x * 4 + wave;
    const float4* xrow = (const float4*)(x + (size_t)token * D_IN);
    float xf[32];
#pragma unroll
    for (int c = 0; c < 8; c++) {
        float4 xc = xrow[lane + 64 * c];
        xf[c * 4 + 0] = xc.x; xf[c * 4 + 1] = xc.y;
        xf[c * 4 + 2] = xc.z; xf[c * 4 + 3] = xc.w;
    }
    float acc[32];
#pragma unroll
    for (int k = 0; k < 32; k++) acc[k] = 0.f;
    int cur = 0;
#pragma unroll
    for (int l = 0; l < DEPTHP1; l++) {
        const float4* wrow = (const float4*)(w_in + (size_t)cur * D_IN);
        float part = 0.f;
#pragma unroll
        for (int c = 0; c < 8; c++) {
            float4 wc = wrow[lane + 64 * c];
            part += wc.x * xf[c * 4 + 0]; part += wc.y * xf[c * 4 + 1];
            part += wc.z * xf[c * 4 + 2]; part += wc.w * xf[c * 4 + 3];
        }
#pragma unroll
        for (int off = 32; off >= 1; off >>= 1) part += __shfl_xor(part, off, 64);
        const float score = part;
        const float g = 0.5f * score * (1.0f + erff(score * 0.70710678118654752f));
        if (TRANSPOSED) {
            const float4* orow = (const float4*)(w_out + (size_t)cur * D_OUT);
#pragma unroll
            for (int c = 0; c < 8; c++) {
                float4 oc = orow[lane + 64 * c];
                acc[c * 4 + 0] += g * oc.x; acc[c * 4 + 1] += g * oc.y;
                acc[c * 4 + 2] += g * oc.z; acc[c * 4 + 3] += g * oc.w;
            }
        } else {
#pragma unroll
            for (int c = 0; c < 8; c++)
#pragma unroll
                for (int k = 0; k < 4; k++) {
                    const int j = (lane + 64 * c) * 4 + k;
                    acc[c * 4 + k] += g * w_out[(size_t)j * N_NODES + cur];
                }
        }
        cur = 2 * cur + 1 + (score >= 0.f ? 1 : 0);
    }
    float4* outrow = (float4*)(out + (size_t)token * D_OUT);
#pragma unroll
    for (int c = 0; c < 8; c++) {
        float4 o;
        o.x = acc[c * 4 + 0]; o.y = acc[c * 4 + 1];
        o.z = acc[c * 4 + 2]; o.w = acc[c * 4 + 3];
        outrow[lane + 64 * c] = o;
    }
}

extern "C" void kernel_launch(void* const* d_in, const int* in_sizes, int n_in,
                              void* d_out, int out_size, void* d_ws, size_t ws_size,
                              hipStream_t stream) {
    (void)in_sizes; (void)n_in; (void)out_size;
    const float* x     = (const float*)d_in[0];
    const float* w_in  = (const float*)d_in[1];
    const float* w_out = (const float*)d_in[2];
    float* out = (float*)d_out;

    const size_t wt_bytes   = (size_t)N_NODES * D_OUT * sizeof(float);   // 33.546 MB
    const size_t g_bytes    = (size_t)N_TOK * DEPTHP1 * sizeof(float);   // 393 KB
    const size_t leaf_bytes = (size_t)N_TOK * sizeof(int);
    const size_t ord_bytes  = (size_t)N_TOK * sizeof(int);
    const size_t hc_bytes   = (size_t)(2 * N_LEAF) * sizeof(int);
    const size_t gs_bytes   = g_bytes;
    const size_t lfs_bytes  = (size_t)N_TOK * sizeof(int);
    const size_t need = wt_bytes + g_bytes + leaf_bytes + ord_bytes +
                        hc_bytes + gs_bytes + lfs_bytes + 64;

    if (ws_size >= need) {
        char* p = (char*)d_ws;
        float* w_out_t  = (float*)p;  p += wt_bytes;
        float* g_all    = (float*)p;  p += g_bytes;
        int*   leaf     = (int*)p;    p += leaf_bytes;
        int*   order    = (int*)p;    p += ord_bytes;
        int*   hc       = (int*)p;    p += hc_bytes;    // hist[2048] cnt[2048]
        float* g_sorted = (float*)p;  p += gs_bytes;
        int*   lf_sorted= (int*)p;

        void* args[] = {
            (void*)&x, (void*)&w_in, (void*)&w_out, (void*)&w_out_t,
            (void*)&g_all, (void*)&leaf, (void*)&hc, (void*)&order,
            (void*)&g_sorted, (void*)&lf_sorted, (void*)&out};
        hipError_t e = hipLaunchCooperativeKernel(
            (const void*)fff_mega, dim3(MEGA_G), dim3(256), args,
            32768, stream);
        if (e != hipSuccess) {
            // Fallback: proven R13 4-launch pipeline (bit-identical math).
            transpose_wout64z<<<dim3(64, 32), dim3(64, 4), 0, stream>>>(
                w_out, w_out_t, hc);
            phaseA<<<N_TOK / 4, 256, 4 * D_IN * sizeof(float), stream>>>(
                x, w_in, g_all, leaf, hc);
            scatter_scan<<<N_TOK / 256, 256, 0, stream>>>(
                leaf, hc, hc + N_LEAF, g_all, order, g_sorted, lf_sorted);
            phaseB_cols<<<2048, 256, 0, stream>>>(w_out_t, g_sorted, order,
                                                  lf_sorted, out);
        }
    } else if (ws_size >= wt_bytes) {
        float* w_out_t = (float*)d_ws;
        transpose_wout64<<<dim3((N_NODES + 63) / 64, D_OUT / 64), dim3(64, 4),
                           0, stream>>>(w_out, w_out_t);
        fff_fused<true><<<N_TOK / 4, 256, 0, stream>>>(x, w_in, w_out_t, out);
    } else {
        fff_fused<false><<<N_TOK / 4, 256, 0, stream>>>(x, w_in, w_out, out);
    }
}